// Round 1
// baseline (75.551 us; speedup 1.0000x reference)
//
#include <hip/hip_runtime.h>

#define NSCENE 64
#define NPTS   16384
#define SIN    256
#define SH     128
#define SOUT   128
#define TILE_P 32

typedef __attribute__((ext_vector_type(8))) short bf16x8;
typedef __attribute__((ext_vector_type(4))) float f32x4;

__device__ __forceinline__ short f2bf(float f) {
  // RTNE f32 -> bf16 (bit pattern)
  unsigned int u = __float_as_uint(f);
  unsigned int r = (u + 0x7FFFu + ((u >> 16) & 1u)) >> 16;
  return (short)(r & 0xFFFFu);
}

// ---------------- bucketing ----------------

__global__ void hist_kernel(const int* __restrict__ bidx, int* __restrict__ counts) {
  __shared__ int lh[NSCENE];
  int tid = threadIdx.x;
  if (tid < NSCENE) lh[tid] = 0;
  __syncthreads();
  int n = blockIdx.x * blockDim.x + tid;
  atomicAdd(&lh[bidx[n]], 1);
  __syncthreads();
  if (tid < NSCENE && lh[tid] > 0) atomicAdd(&counts[tid], lh[tid]);
}

__global__ void scan_kernel(const int* __restrict__ counts, int* __restrict__ offsets,
                            int* __restrict__ cursors) {
  int lane = threadIdx.x;          // 64 threads = 1 wave
  int c = counts[lane];
  int v = c;
  for (int off = 1; off < 64; off <<= 1) {
    int t = __shfl_up(v, off);
    if (lane >= off) v += t;
  }
  offsets[lane + 1] = v;           // inclusive
  if (lane == 0) offsets[0] = 0;
  cursors[lane] = v - c;           // exclusive
}

__global__ void scatter_kernel(const int* __restrict__ bidx, int* __restrict__ cursors,
                               int* __restrict__ perm) {
  int n = blockIdx.x * blockDim.x + threadIdx.x;
  int s = bidx[n];
  int pos = atomicAdd(&cursors[s], 1);
  perm[pos] = n;
}

// ---------------- fused per-scene GEMM ----------------
// block = (scene s, point-tile t of 32). 256 threads = 4 waves.
// wave w owns output cols [w*32, w*32+32), all 32 rows (2 M-tiles x 2 N-tiles).

__global__ __launch_bounds__(256) void fused_kernel(
    const float* __restrict__ kls0, const float* __restrict__ kls1,
    const float* __restrict__ kls2, const float* __restrict__ bias0,
    const float* __restrict__ bias1, const float* __restrict__ x,
    const int* __restrict__ offsets, const int* __restrict__ perm,
    float* __restrict__ out)
{
  __shared__ __align__(16) short xr[TILE_P][SIN + 8];   // relu(x) bf16, padded rows
  __shared__ __align__(16) short xp[TILE_P][SIN + 8];   // x bf16
  __shared__ __align__(16) short snet[TILE_P][SH + 8];  // relu(net) bf16
  __shared__ int ptile[TILE_P];

  const int s    = blockIdx.x;
  const int base = offsets[s];
  const int cnt  = offsets[s + 1] - base;
  const int tid  = threadIdx.x;
  const int lane = tid & 63;
  const int w    = tid >> 6;
  const int l15  = lane & 15;
  const int lh4  = lane >> 4;

  const float* W0 = kls0 + (size_t)s * SH * SIN;
  const float* W1 = kls1 + (size_t)s * SOUT * SH;
  const float* W2 = kls2 + (size_t)s * SOUT * SIN;

  for (int t = blockIdx.y; t * TILE_P < cnt; t += gridDim.y) {
    __syncthreads();  // protect LDS reuse across tile iterations

    // ---- stage x tile: 8 threads per row, 32 floats each ----
    {
      int r  = tid >> 3;
      int cg = tid & 7;
      int prow = t * TILE_P + r;
      int np = (prow < cnt) ? perm[base + prow] : -1;
      if (cg == 0) ptile[r] = np;
      const float* xrow = x + (size_t)(np < 0 ? 0 : np) * SIN;
      int c0 = cg * 32;
      for (int j = 0; j < 32; j += 4) {
        float4 v = make_float4(0.f, 0.f, 0.f, 0.f);
        if (np >= 0) v = *reinterpret_cast<const float4*>(xrow + c0 + j);
        short4 p, q;
        p.x = f2bf(v.x); p.y = f2bf(v.y); p.z = f2bf(v.z); p.w = f2bf(v.w);
        q.x = f2bf(fmaxf(v.x, 0.f)); q.y = f2bf(fmaxf(v.y, 0.f));
        q.z = f2bf(fmaxf(v.z, 0.f)); q.w = f2bf(fmaxf(v.w, 0.f));
        *reinterpret_cast<short4*>(&xp[r][c0 + j]) = p;
        *reinterpret_cast<short4*>(&xr[r][c0 + j]) = q;
      }
    }
    __syncthreads();

    // ---- layer 0: net = relu(x) @ W0^T + bias0 ----
    f32x4 acc0[2][2];
    for (int nt2 = 0; nt2 < 2; ++nt2) {
      float bv = bias0[(size_t)s * SH + w * 32 + nt2 * 16 + l15];
      for (int mt = 0; mt < 2; ++mt) acc0[mt][nt2] = (f32x4){bv, bv, bv, bv};
    }
    for (int ks = 0; ks < 8; ++ks) {
      int kc = ks * 32 + lh4 * 8;
      bf16x8 bfrag[2];
      for (int nt2 = 0; nt2 < 2; ++nt2) {
        const float* wr = W0 + (size_t)(w * 32 + nt2 * 16 + l15) * SIN + kc;
        float4 u0 = *reinterpret_cast<const float4*>(wr);
        float4 u1 = *reinterpret_cast<const float4*>(wr + 4);
        bfrag[nt2] = (bf16x8){f2bf(u0.x), f2bf(u0.y), f2bf(u0.z), f2bf(u0.w),
                              f2bf(u1.x), f2bf(u1.y), f2bf(u1.z), f2bf(u1.w)};
      }
      for (int mt = 0; mt < 2; ++mt) {
        bf16x8 afrag = *reinterpret_cast<const bf16x8*>(&xr[mt * 16 + l15][kc]);
        for (int nt2 = 0; nt2 < 2; ++nt2)
          acc0[mt][nt2] = __builtin_amdgcn_mfma_f32_16x16x32_bf16(
              afrag, bfrag[nt2], acc0[mt][nt2], 0, 0, 0);
      }
    }
    // write relu(net) -> LDS (D layout: row=(lane>>4)*4+reg, col=lane&15)
    for (int mt = 0; mt < 2; ++mt)
      for (int nt2 = 0; nt2 < 2; ++nt2)
        for (int r4 = 0; r4 < 4; ++r4)
          snet[mt * 16 + lh4 * 4 + r4][w * 32 + nt2 * 16 + l15] =
              f2bf(fmaxf(acc0[mt][nt2][r4], 0.f));

    // ---- layer 2 (shortcut, reads xp; overlaps the snet barrier) ----
    f32x4 acc[2][2];
    for (int nt2 = 0; nt2 < 2; ++nt2) {
      float bv = bias1[(size_t)s * SOUT + w * 32 + nt2 * 16 + l15];
      for (int mt = 0; mt < 2; ++mt) acc[mt][nt2] = (f32x4){bv, bv, bv, bv};
    }
    for (int ks = 0; ks < 8; ++ks) {
      int kc = ks * 32 + lh4 * 8;
      bf16x8 bfrag[2];
      for (int nt2 = 0; nt2 < 2; ++nt2) {
        const float* wr = W2 + (size_t)(w * 32 + nt2 * 16 + l15) * SIN + kc;
        float4 u0 = *reinterpret_cast<const float4*>(wr);
        float4 u1 = *reinterpret_cast<const float4*>(wr + 4);
        bfrag[nt2] = (bf16x8){f2bf(u0.x), f2bf(u0.y), f2bf(u0.z), f2bf(u0.w),
                              f2bf(u1.x), f2bf(u1.y), f2bf(u1.z), f2bf(u1.w)};
      }
      for (int mt = 0; mt < 2; ++mt) {
        bf16x8 afrag = *reinterpret_cast<const bf16x8*>(&xp[mt * 16 + l15][kc]);
        for (int nt2 = 0; nt2 < 2; ++nt2)
          acc[mt][nt2] = __builtin_amdgcn_mfma_f32_16x16x32_bf16(
              afrag, bfrag[nt2], acc[mt][nt2], 0, 0, 0);
      }
    }
    __syncthreads();  // snet ready

    // ---- layer 1: acc += relu(net) @ W1^T ----
    for (int ks = 0; ks < 4; ++ks) {
      int kc = ks * 32 + lh4 * 8;
      bf16x8 bfrag[2];
      for (int nt2 = 0; nt2 < 2; ++nt2) {
        const float* wr = W1 + (size_t)(w * 32 + nt2 * 16 + l15) * SH + kc;
        float4 u0 = *reinterpret_cast<const float4*>(wr);
        float4 u1 = *reinterpret_cast<const float4*>(wr + 4);
        bfrag[nt2] = (bf16x8){f2bf(u0.x), f2bf(u0.y), f2bf(u0.z), f2bf(u0.w),
                              f2bf(u1.x), f2bf(u1.y), f2bf(u1.z), f2bf(u1.w)};
      }
      for (int mt = 0; mt < 2; ++mt) {
        bf16x8 afrag = *reinterpret_cast<const bf16x8*>(&snet[mt * 16 + l15][kc]);
        for (int nt2 = 0; nt2 < 2; ++nt2)
          acc[mt][nt2] = __builtin_amdgcn_mfma_f32_16x16x32_bf16(
              afrag, bfrag[nt2], acc[mt][nt2], 0, 0, 0);
      }
    }

    // ---- store ----
    for (int mt = 0; mt < 2; ++mt)
      for (int r4 = 0; r4 < 4; ++r4) {
        int row = mt * 16 + lh4 * 4 + r4;
        int pt = ptile[row];
        if (pt >= 0) {
          for (int nt2 = 0; nt2 < 2; ++nt2)
            out[(size_t)pt * SOUT + w * 32 + nt2 * 16 + l15] = acc[mt][nt2][r4];
        }
      }
  }
}

// ---------------- launch ----------------

extern "C" void kernel_launch(void* const* d_in, const int* in_sizes, int n_in,
                              void* d_out, int out_size, void* d_ws, size_t ws_size,
                              hipStream_t stream) {
  const float* kls0  = (const float*)d_in[0];
  const float* kls1  = (const float*)d_in[1];
  const float* kls2  = (const float*)d_in[2];
  const float* bias0 = (const float*)d_in[3];
  const float* bias1 = (const float*)d_in[4];
  const float* x     = (const float*)d_in[5];
  const int*   bidx  = (const int*)d_in[6];
  float* out = (float*)d_out;

  int* counts  = (int*)d_ws;       // 64
  int* offsets = counts + 64;      // 65
  int* cursors = offsets + 72;     // 64
  int* perm    = cursors + 64;     // 16384

  hipMemsetAsync(counts, 0, NSCENE * sizeof(int), stream);
  hist_kernel<<<NPTS / 256, 256, 0, stream>>>(bidx, counts);
  scan_kernel<<<1, 64, 0, stream>>>(counts, offsets, cursors);
  scatter_kernel<<<NPTS / 256, 256, 0, stream>>>(bidx, cursors, perm);
  fused_kernel<<<dim3(NSCENE, 12), 256, 0, stream>>>(kls0, kls1, kls2, bias0, bias1,
                                                     x, offsets, perm, out);
}

// Round 2
// 35.033 us; speedup vs baseline: 2.1565x; 2.1565x over previous
//
#include <hip/hip_runtime.h>

#define NSCENE 64
#define NPTS   16384
#define SIN    256
#define SH     128
#define SOUT   128
#define TILE_P 32

// ---- workspace layout (bytes) ----
#define WS_PARTIAL 0              // 64*64 int  (per-block partial histograms)
#define WS_OFFSETS 16384          // 65 int
#define WS_PERM    17408          // 16384 int
#define WS_WBF16   82944          // 5,242,880 shorts = 10,485,760 B (bf16 weights)
#define W0_ELEMS   (NSCENE*SH*SIN)    // 2,097,152
#define W1_ELEMS   (NSCENE*SOUT*SH)   // 1,048,576
#define W2_ELEMS   (NSCENE*SOUT*SIN)  // 2,097,152
#define WTOT       (W0_ELEMS+W1_ELEMS+W2_ELEMS)  // 5,242,880
#define CONV_BLOCKS 2560          // WTOT / (256 threads * 8 elems)

typedef __attribute__((ext_vector_type(8))) short bf16x8;
typedef __attribute__((ext_vector_type(4))) float f32x4;

__device__ __forceinline__ short f2bf(float f) {
  unsigned int u = __float_as_uint(f);
  unsigned int r = (u + 0x7FFFu + ((u >> 16) & 1u)) >> 16;
  return (short)(r & 0xFFFFu);
}

// ---------------- K1: partial histograms + weight bf16 conversion ----------------

__global__ __launch_bounds__(256) void prep_kernel(
    const int* __restrict__ bidx,
    const float* __restrict__ kls0, const float* __restrict__ kls1,
    const float* __restrict__ kls2,
    int* __restrict__ partial, short* __restrict__ wb)
{
  int b = blockIdx.x;
  int tid = threadIdx.x;
  if (b < 64) {
    __shared__ int lh[NSCENE];
    if (tid < NSCENE) lh[tid] = 0;
    __syncthreads();
    atomicAdd(&lh[bidx[b * 256 + tid]], 1);
    __syncthreads();
    if (tid < NSCENE) partial[b * 64 + tid] = lh[tid];
  } else {
    int g = (b - 64) * 256 + tid;    // convert-thread id; 8 floats each
    int e = g * 8;
    if (e < WTOT) {
      const float* src;
      if (e < W0_ELEMS) src = kls0 + e;
      else if (e < W0_ELEMS + W1_ELEMS) src = kls1 + (e - W0_ELEMS);
      else src = kls2 + (e - W0_ELEMS - W1_ELEMS);
      float4 u0 = *reinterpret_cast<const float4*>(src);
      float4 u1 = *reinterpret_cast<const float4*>(src + 4);
      bf16x8 v = (bf16x8){f2bf(u0.x), f2bf(u0.y), f2bf(u0.z), f2bf(u0.w),
                          f2bf(u1.x), f2bf(u1.y), f2bf(u1.z), f2bf(u1.w)};
      *reinterpret_cast<bf16x8*>(wb + e) = v;
    }
  }
}

// ---------------- K2: in-block scan + scatter (no global atomics) ----------------

__global__ __launch_bounds__(256) void scatter_kernel(
    const int* __restrict__ bidx, const int* __restrict__ partial,
    int* __restrict__ offsets, int* __restrict__ perm)
{
  __shared__ int cur[NSCENE];
  int b = blockIdx.x;
  int tid = threadIdx.x;
  if (tid < 64) {               // wave 0 computes bases
    int s = tid;
    int colpre = 0, total = 0;
    for (int bb = 0; bb < 64; ++bb) {
      int v = partial[bb * 64 + s];
      if (bb < b) colpre += v;
      total += v;
    }
    int v = total;               // inclusive scan over scenes
    for (int off = 1; off < 64; off <<= 1) {
      int t = __shfl_up(v, off);
      if (s >= off) v += t;
    }
    int sceneoff = v - total;    // exclusive
    cur[s] = sceneoff + colpre;
    if (b == 0) {
      offsets[s] = sceneoff;
      if (s == 63) offsets[64] = NPTS;
    }
  }
  __syncthreads();
  int n = b * 256 + tid;
  int s = bidx[n];
  int pos = atomicAdd(&cur[s], 1);   // LDS atomic, block-local
  perm[pos] = n;
}

// ---------------- K3: fused per-scene GEMM ----------------
// 1-D grid of 512: g = t0*64 + s  => g%8 == s%8 (XCD-pinned scenes).
// 256 threads = 4 waves; wave w owns cols [w*32, w*32+32) of a 32-point tile.

template<bool BF16W>
__global__ __launch_bounds__(256) void fused_kernel(
    const float* __restrict__ kls0, const float* __restrict__ kls1,
    const float* __restrict__ kls2, const float* __restrict__ bias0,
    const float* __restrict__ bias1, const float* __restrict__ x,
    const int* __restrict__ offsets, const int* __restrict__ perm,
    const short* __restrict__ wb, float* __restrict__ out)
{
  __shared__ __align__(16) short xr[TILE_P][SIN + 8];   // relu(x) bf16
  __shared__ __align__(16) short xp[TILE_P][SIN + 8];   // x bf16
  __shared__ __align__(16) short snet[TILE_P][SH + 8];  // relu(net) bf16
  __shared__ int ptile[TILE_P];

  const int s    = blockIdx.x & 63;
  const int t0   = blockIdx.x >> 6;
  const int base = offsets[s];
  const int cnt  = offsets[s + 1] - base;
  const int tid  = threadIdx.x;
  const int lane = tid & 63;
  const int w    = tid >> 6;
  const int l15  = lane & 15;
  const int lh4  = lane >> 4;

  const float* W0 = kls0 + (size_t)s * SH * SIN;
  const float* W1 = kls1 + (size_t)s * SOUT * SH;
  const float* W2 = kls2 + (size_t)s * SOUT * SIN;
  const short* B0 = wb + (size_t)s * SH * SIN;
  const short* B1 = wb + W0_ELEMS + (size_t)s * SOUT * SH;
  const short* B2 = wb + W0_ELEMS + W1_ELEMS + (size_t)s * SOUT * SIN;

  for (int t = t0; t * TILE_P < cnt; t += 8) {
    __syncthreads();

    // ---- stage x tile: 8 threads per row, 32 floats each ----
    {
      int r  = tid >> 3;
      int cg = tid & 7;
      int prow = t * TILE_P + r;
      int np = (prow < cnt) ? perm[base + prow] : -1;
      if (cg == 0) ptile[r] = np;
      const float* xrow = x + (size_t)(np < 0 ? 0 : np) * SIN;
      int c0 = cg * 32;
      for (int j = 0; j < 32; j += 4) {
        float4 v = make_float4(0.f, 0.f, 0.f, 0.f);
        if (np >= 0) v = *reinterpret_cast<const float4*>(xrow + c0 + j);
        short4 p, q;
        p.x = f2bf(v.x); p.y = f2bf(v.y); p.z = f2bf(v.z); p.w = f2bf(v.w);
        q.x = f2bf(fmaxf(v.x, 0.f)); q.y = f2bf(fmaxf(v.y, 0.f));
        q.z = f2bf(fmaxf(v.z, 0.f)); q.w = f2bf(fmaxf(v.w, 0.f));
        *reinterpret_cast<short4*>(&xp[r][c0 + j]) = p;
        *reinterpret_cast<short4*>(&xr[r][c0 + j]) = q;
      }
    }
    __syncthreads();

    // ---- layer 0: net = relu(x) @ W0^T + bias0 ----
    f32x4 acc0[2][2];
    for (int nt2 = 0; nt2 < 2; ++nt2) {
      float bv = bias0[(size_t)s * SH + w * 32 + nt2 * 16 + l15];
      for (int mt = 0; mt < 2; ++mt) acc0[mt][nt2] = (f32x4){bv, bv, bv, bv};
    }
    for (int ks = 0; ks < 8; ++ks) {
      int kc = ks * 32 + lh4 * 8;
      bf16x8 bfrag[2];
      for (int nt2 = 0; nt2 < 2; ++nt2) {
        int row = w * 32 + nt2 * 16 + l15;
        if constexpr (BF16W) {
          bfrag[nt2] = *reinterpret_cast<const bf16x8*>(B0 + (size_t)row * SIN + kc);
        } else {
          const float* wr = W0 + (size_t)row * SIN + kc;
          float4 u0 = *reinterpret_cast<const float4*>(wr);
          float4 u1 = *reinterpret_cast<const float4*>(wr + 4);
          bfrag[nt2] = (bf16x8){f2bf(u0.x), f2bf(u0.y), f2bf(u0.z), f2bf(u0.w),
                                f2bf(u1.x), f2bf(u1.y), f2bf(u1.z), f2bf(u1.w)};
        }
      }
      for (int mt = 0; mt < 2; ++mt) {
        bf16x8 afrag = *reinterpret_cast<const bf16x8*>(&xr[mt * 16 + l15][kc]);
        for (int nt2 = 0; nt2 < 2; ++nt2)
          acc0[mt][nt2] = __builtin_amdgcn_mfma_f32_16x16x32_bf16(
              afrag, bfrag[nt2], acc0[mt][nt2], 0, 0, 0);
      }
    }
    for (int mt = 0; mt < 2; ++mt)
      for (int nt2 = 0; nt2 < 2; ++nt2)
        for (int r4 = 0; r4 < 4; ++r4)
          snet[mt * 16 + lh4 * 4 + r4][w * 32 + nt2 * 16 + l15] =
              f2bf(fmaxf(acc0[mt][nt2][r4], 0.f));

    // ---- layer 2 (shortcut) overlaps the snet barrier ----
    f32x4 acc[2][2];
    for (int nt2 = 0; nt2 < 2; ++nt2) {
      float bv = bias1[(size_t)s * SOUT + w * 32 + nt2 * 16 + l15];
      for (int mt = 0; mt < 2; ++mt) acc[mt][nt2] = (f32x4){bv, bv, bv, bv};
    }
    for (int ks = 0; ks < 8; ++ks) {
      int kc = ks * 32 + lh4 * 8;
      bf16x8 bfrag[2];
      for (int nt2 = 0; nt2 < 2; ++nt2) {
        int row = w * 32 + nt2 * 16 + l15;
        if constexpr (BF16W) {
          bfrag[nt2] = *reinterpret_cast<const bf16x8*>(B2 + (size_t)row * SIN + kc);
        } else {
          const float* wr = W2 + (size_t)row * SIN + kc;
          float4 u0 = *reinterpret_cast<const float4*>(wr);
          float4 u1 = *reinterpret_cast<const float4*>(wr + 4);
          bfrag[nt2] = (bf16x8){f2bf(u0.x), f2bf(u0.y), f2bf(u0.z), f2bf(u0.w),
                                f2bf(u1.x), f2bf(u1.y), f2bf(u1.z), f2bf(u1.w)};
        }
      }
      for (int mt = 0; mt < 2; ++mt) {
        bf16x8 afrag = *reinterpret_cast<const bf16x8*>(&xp[mt * 16 + l15][kc]);
        for (int nt2 = 0; nt2 < 2; ++nt2)
          acc[mt][nt2] = __builtin_amdgcn_mfma_f32_16x16x32_bf16(
              afrag, bfrag[nt2], acc[mt][nt2], 0, 0, 0);
      }
    }
    __syncthreads();  // snet ready

    // ---- layer 1: acc += relu(net) @ W1^T ----
    for (int ks = 0; ks < 4; ++ks) {
      int kc = ks * 32 + lh4 * 8;
      bf16x8 bfrag[2];
      for (int nt2 = 0; nt2 < 2; ++nt2) {
        int row = w * 32 + nt2 * 16 + l15;
        if constexpr (BF16W) {
          bfrag[nt2] = *reinterpret_cast<const bf16x8*>(B1 + (size_t)row * SH + kc);
        } else {
          const float* wr = W1 + (size_t)row * SH + kc;
          float4 u0 = *reinterpret_cast<const float4*>(wr);
          float4 u1 = *reinterpret_cast<const float4*>(wr + 4);
          bfrag[nt2] = (bf16x8){f2bf(u0.x), f2bf(u0.y), f2bf(u0.z), f2bf(u0.w),
                                f2bf(u1.x), f2bf(u1.y), f2bf(u1.z), f2bf(u1.w)};
        }
      }
      for (int mt = 0; mt < 2; ++mt) {
        bf16x8 afrag = *reinterpret_cast<const bf16x8*>(&snet[mt * 16 + l15][kc]);
        for (int nt2 = 0; nt2 < 2; ++nt2)
          acc[mt][nt2] = __builtin_amdgcn_mfma_f32_16x16x32_bf16(
              afrag, bfrag[nt2], acc[mt][nt2], 0, 0, 0);
      }
    }

    // ---- store ----
    for (int mt = 0; mt < 2; ++mt)
      for (int r4 = 0; r4 < 4; ++r4) {
        int row = mt * 16 + lh4 * 4 + r4;
        int pt = ptile[row];
        if (pt >= 0) {
          for (int nt2 = 0; nt2 < 2; ++nt2)
            out[(size_t)pt * SOUT + w * 32 + nt2 * 16 + l15] = acc[mt][nt2][r4];
        }
      }
  }
}

// ---------------- launch ----------------

extern "C" void kernel_launch(void* const* d_in, const int* in_sizes, int n_in,
                              void* d_out, int out_size, void* d_ws, size_t ws_size,
                              hipStream_t stream) {
  const float* kls0  = (const float*)d_in[0];
  const float* kls1  = (const float*)d_in[1];
  const float* kls2  = (const float*)d_in[2];
  const float* bias0 = (const float*)d_in[3];
  const float* bias1 = (const float*)d_in[4];
  const float* x     = (const float*)d_in[5];
  const int*   bidx  = (const int*)d_in[6];
  float* out = (float*)d_out;

  int*   partial = (int*)((char*)d_ws + WS_PARTIAL);
  int*   offsets = (int*)((char*)d_ws + WS_OFFSETS);
  int*   perm    = (int*)((char*)d_ws + WS_PERM);
  short* wb      = (short*)((char*)d_ws + WS_WBF16);

  bool bf16w = ws_size >= (size_t)WS_WBF16 + sizeof(short) * (size_t)WTOT;

  prep_kernel<<<bf16w ? (64 + CONV_BLOCKS) : 64, 256, 0, stream>>>(
      bidx, kls0, kls1, kls2, partial, wb);
  scatter_kernel<<<64, 256, 0, stream>>>(bidx, partial, offsets, perm);
  if (bf16w)
    fused_kernel<true><<<512, 256, 0, stream>>>(kls0, kls1, kls2, bias0, bias1,
                                                x, offsets, perm, wb, out);
  else
    fused_kernel<false><<<512, 256, 0, stream>>>(kls0, kls1, kls2, bias0, bias1,
                                                 x, offsets, perm, wb, out);
}